// Round 6
// baseline (97.762 us; speedup 1.0000x reference)
//
#include <hip/hip_runtime.h>

// Pool_layer: B=4, N=8192, C=256, NEIGHBOR_NUM=4, P=N/4=2048
// d_out = vertices_pool (B,P,3) fp32 || feature_map_pool (B,P,C) fp32.
//
// Reference: neighbors of query n = the 4 SMALLEST indices m with
// dist2(n,m) <= r^2 (self forced via zeroed diagonal), padded with first hit.
// dist2 in the reference's exact fp32 order (FMA contraction blocked).
//
// R5 -> R6: straggler fixes plateaued at ~22us -> common path dominates.
// Every wave was issuing ~24 global loads with 12B lane stride (12 cache
// lines per instr) over a slab all 2048 waves/batch re-read. Fix:
//   - block stages first 1024 candidates' xyz into LDS (12KB) with 3
//     coalesced float4 loads per thread; waves scan from LDS (2-way bank
//     aliasing = free on gfx950).
//   - stage 2 (rare): R5's lane-parallel global scan + shfl-min merge,
//     now with hit-count early exit (ascending scan => once >=4 hits seen,
//     the 4 smallest are already in hand).

#define BB 4
#define NN 8192
#define CC 256
#define PP 2048
#define KK 4
#define SS 1024           // candidates staged in LDS (stage 1 window)
#define CH2 16            // stage 2: 1024 candidates per round

__device__ __forceinline__ float dist_ref(float xn0, float xn1, float xn2, float sqn,
                                          float x0, float x1, float x2) {
    // sq_m = ((x*x)+(y*y))+(z*z); dot likewise; dist = (-2*dot)+sq_n+sq_m
    const float sqm = __fadd_rn(__fadd_rn(__fmul_rn(x0, x0), __fmul_rn(x1, x1)),
                                __fmul_rn(x2, x2));
    const float dot = __fadd_rn(__fadd_rn(__fmul_rn(xn0, x0), __fmul_rn(xn1, x1)),
                                __fmul_rn(xn2, x2));
    return __fadd_rn(__fadd_rn(__fmul_rn(-2.0f, dot), sqn), sqm);
}

__global__ __launch_bounds__(256) void pool_layer_kernel(
    const float* __restrict__ vertices,   // (B, N, 3)
    const float* __restrict__ feat,       // (B, N, C)
    const int*   __restrict__ radius_p,   // (1,)
    const int*   __restrict__ sample_idx, // (P,)
    float* __restrict__ out_v,            // (B, P, 3)
    float* __restrict__ out_f)            // (B, P, C)
{
    __shared__ float s_v[SS * 3];         // 12 KB: xyz of candidates 0..1023

    const int tid  = threadIdx.x;
    const int wave = tid >> 6;
    const int lane = tid & 63;
    const int q    = blockIdx.x * 4 + wave;   // [0, B*P); all 4 share b
    const int b    = q >> 11;
    const int i    = q & (PP - 1);
    const float* vb = vertices + (size_t)b * NN * 3;

    // ---- cooperative staging: 12KB = 768 float4, 3 per thread, coalesced ----
    const float4* v4 = (const float4*)vb;     // base is 16B-aligned
    const float4 st0 = v4[tid];
    const float4 st1 = v4[tid + 256];
    const float4 st2 = v4[tid + 512];

    // query chain overlaps the staging loads
    const int n = sample_idx[i];
    const float xn0 = vb[n * 3 + 0];
    const float xn1 = vb[n * 3 + 1];
    const float xn2 = vb[n * 3 + 2];
    const float sqn = __fadd_rn(__fadd_rn(__fmul_rn(xn0, xn0), __fmul_rn(xn1, xn1)),
                                __fmul_rn(xn2, xn2));
    const int   r  = radius_p[0];
    const float r2 = (float)(r * r);

    ((float4*)s_v)[tid]       = st0;
    ((float4*)s_v)[tid + 256] = st1;
    ((float4*)s_v)[tid + 512] = st2;

    // vertices_pool gather
    if (lane < 3) out_v[((size_t)b * PP + i) * 3 + lane] = vb[n * 3 + lane];

    __syncthreads();

    // ---- stage 1: first 1024 candidates from LDS ----
    int c0 = 0, c1 = 0, c2 = 0, c3 = 0, cnt = 0;
    #pragma unroll
    for (int c = 0; c < SS / 64; ++c) {
        const int m = c * 64 + lane;
        const float x0 = s_v[m * 3 + 0];
        const float x1 = s_v[m * 3 + 1];
        const float x2 = s_v[m * 3 + 2];
        const float dist = dist_ref(xn0, xn1, xn2, sqn, x0, x1, x2);
        unsigned long long mask = __ballot((m == n) || !(dist > r2));
        while (mask && cnt < KK) {            // wave-uniform scalar pops
            const int v = c * 64 + (__ffsll(mask) - 1);
            c3 = (cnt == 3) ? v : c3;
            c2 = (cnt == 2) ? v : c2;
            c1 = (cnt == 1) ? v : c1;
            c0 = (cnt == 0) ? v : c0;
            ++cnt;
            mask &= (mask - 1);
        }
    }

    // ---- stage 2 (wave-uniform, rare): lane-parallel global rescan ----
    if (cnt < KK) {
        int l0 = NN, l1 = NN, l2 = NN, l3 = NN, lcnt = 0;
        int tot = 0;   // wave-uniform running hit count (ascending scan:
                       // once tot>=4 the 4 smallest are already held)
        for (int base = 0; base < NN && tot < KK; base += 64 * CH2) {
            float qx[CH2], qy[CH2], qz[CH2];
            #pragma unroll
            for (int c = 0; c < CH2; ++c) {
                const int m = base + c * 64 + lane;
                qx[c] = vb[m * 3 + 0];
                qy[c] = vb[m * 3 + 1];
                qz[c] = vb[m * 3 + 2];
            }
            #pragma unroll
            for (int c = 0; c < CH2; ++c) {
                const int m = base + c * 64 + lane;
                const float dist = dist_ref(xn0, xn1, xn2, sqn, qx[c], qy[c], qz[c]);
                const bool hit = (m == n) || !(dist > r2);
                tot += (int)__popcll(__ballot(hit));
                if (hit && lcnt < KK) {        // per-lane ascending first-4
                    l3 = (lcnt == 3) ? m : l3;
                    l2 = (lcnt == 2) ? m : l2;
                    l1 = (lcnt == 1) ? m : l1;
                    l0 = (lcnt == 0) ? m : l0;
                    ++lcnt;
                }
            }
        }
        // k-way merge: 4 rounds of min-of-heads + pop-on-match
        int g[KK];
        #pragma unroll
        for (int round = 0; round < KK; ++round) {
            int mmin = l0;
            #pragma unroll
            for (int off = 32; off > 0; off >>= 1)
                mmin = min(mmin, __shfl_xor(mmin, off));
            g[round] = mmin;                   // wave-uniform
            if (l0 == mmin) { l0 = l1; l1 = l2; l2 = l3; l3 = NN; }
        }
        c0 = g[0];                              // self-hit guarantees validity
        c1 = (g[1] == NN) ? g[0] : g[1];
        c2 = (g[2] == NN) ? g[0] : g[2];
        c3 = (g[3] == NN) ? g[0] : g[3];
    }

    // ---- max-pool 4 feature rows (64 lanes x float4 = one 1KB row each) ----
    const float4 a0 = ((const float4*)(feat + ((size_t)b * NN + c0) * CC))[lane];
    const float4 a1 = ((const float4*)(feat + ((size_t)b * NN + c1) * CC))[lane];
    const float4 a2 = ((const float4*)(feat + ((size_t)b * NN + c2) * CC))[lane];
    const float4 a3 = ((const float4*)(feat + ((size_t)b * NN + c3) * CC))[lane];
    float4 o;
    o.x = fmaxf(fmaxf(a0.x, a1.x), fmaxf(a2.x, a3.x));
    o.y = fmaxf(fmaxf(a0.y, a1.y), fmaxf(a2.y, a3.y));
    o.z = fmaxf(fmaxf(a0.z, a1.z), fmaxf(a2.z, a3.z));
    o.w = fmaxf(fmaxf(a0.w, a1.w), fmaxf(a2.w, a3.w));
    ((float4*)(out_f + ((size_t)b * PP + i) * CC))[lane] = o;
}

extern "C" void kernel_launch(void* const* d_in, const int* in_sizes, int n_in,
                              void* d_out, int out_size, void* d_ws, size_t ws_size,
                              hipStream_t stream) {
    const float* vertices   = (const float*)d_in[0]; // (B,N,3) fp32
    const float* feat       = (const float*)d_in[1]; // (B,N,C) fp32
    const int*   radius_p   = (const int*)d_in[2];   // scalar int
    const int*   sample_idx = (const int*)d_in[3];   // (P,) int32

    float* out_v = (float*)d_out;                    // (B,P,3)
    float* out_f = out_v + (size_t)BB * PP * 3;      // (B,P,C)

    dim3 grid(BB * PP / 4), block(256);              // 1 wave per query
    pool_layer_kernel<<<grid, block, 0, stream>>>(
        vertices, feat, radius_p, sample_idx, out_v, out_f);
}